// Round 23
// baseline (89.830 us; speedup 1.0000x reference)
//
#include <hip/hip_runtime.h>
#include <hip/hip_bf16.h>
#include <math.h>

typedef unsigned short u16;
typedef unsigned int u32;
typedef __attribute__((ext_vector_type(8))) __bf16 bf16x8;
typedef __attribute__((ext_vector_type(4))) float f32x4;

__device__ inline u16 f2bf(float f) {
  u32 b = __float_as_uint(f);
  b += 0x7FFFu + ((b >> 16) & 1u);
  return (u16)(b >> 16);
}
__device__ inline float bf2f(u16 b) { return __uint_as_float((u32)b << 16); }

// async global->LDS, 16 bytes per lane; LDS dest = uniform base + lane*16
__device__ __forceinline__ void gll16(const void* gp, void* lp) {
  __builtin_amdgcn_global_load_lds(
      (const __attribute__((address_space(1))) void*)gp,
      (__attribute__((address_space(3))) void*)lp, 16, 0, 0);
}

// ---------------- fused prep: cvt | weight transposes | rope table ----------
// grid 4224 x 256: [0,1024) cvt x->xb ; [1024,3968) prep_w ; [3968,4224) rope
__global__ __launch_bounds__(256) void prep_all_k(
    const float* __restrict__ x, const int* __restrict__ positions,
    const float* __restrict__ Wq, const float* __restrict__ Wk,
    const float* __restrict__ Wv, const float* __restrict__ Wvr,
    const float* __restrict__ Wo, const float* __restrict__ Wg,
    const float* __restrict__ Wm, u16* __restrict__ xb,
    u16* __restrict__ WallT, u16* __restrict__ WoT, float* __restrict__ rtab) {
  __shared__ float tile[32][33];
  int bid = blockIdx.x, tid = threadIdx.x;
  if (bid < 1024) {  // ---- cvt ----
    int i = (bid * 256 + tid) * 8;
    float4 v0 = *(const float4*)&x[i];
    float4 v1 = *(const float4*)&x[i + 4];
    uint4 pk;
    pk.x = (u32)f2bf(v0.x) | ((u32)f2bf(v0.y) << 16);
    pk.y = (u32)f2bf(v0.z) | ((u32)f2bf(v0.w) << 16);
    pk.z = (u32)f2bf(v1.x) | ((u32)f2bf(v1.y) << 16);
    pk.w = (u32)f2bf(v1.z) | ((u32)f2bf(v1.w) << 16);
    *(uint4*)&xb[i] = pk;
    return;
  }
  if (bid >= 3968) {  // ---- rope table ----
    int idx = (bid - 3968) * 256 + tid;
    int s = idx >> 5, f = idx & 31;
    float inv = __expf(-(float)f * (9.210340371976184f / 32.f));
    float ang = (float)positions[s] * inv;
    rtab[(size_t)s * 64 + f] = cosf(ang);
    rtab[(size_t)s * 64 + 32 + f] = sinf(ang);
    return;
  }
  // ---- weight prep ----
  int b2 = bid - 1024;
  int k0 = (b2 & 31) * 32;
  int ybl = b2 >> 5;
  int tx = tid & 31, ty = tid >> 5;
  const float* src;
  int scol, sN, drow;
  u16* dst;
  if (ybl >= 60) {
    src = Wo; scol = (ybl - 60) * 32; sN = 1024; dst = WoT; drow = scol;
  } else {
    int n0 = ybl * 32;
    if (n0 >= 1792) {  // Wg/Wm/zero region, direct (no LDS)
#pragma unroll
      for (int j = 0; j < 4; ++j) {
        int n = n0 + ty * 4 + j, j2 = n - 1792, k = k0 + tx;
        float val = (j2 < 16) ? Wg[(size_t)k * 16 + j2]
                  : (j2 < 20) ? Wm[(size_t)k * 4 + (j2 - 16)] : 0.f;
        WallT[(size_t)n * 1024 + k] = f2bf(val);
      }
      return;
    }
    dst = WallT; drow = n0;
    if (n0 < 1024) { src = Wq; scol = n0; sN = 1024; }
    else if (n0 < 1280) { src = Wk; scol = n0 - 1024; sN = 256; }
    else if (n0 < 1536) { src = Wv; scol = n0 - 1280; sN = 256; }
    else { src = Wvr; scol = n0 - 1536; sN = 256; }
  }
#pragma unroll
  for (int j = 0; j < 4; ++j)
    tile[ty * 4 + j][tx] = src[(size_t)(k0 + ty * 4 + j) * sN + scol + tx];
  __syncthreads();
#pragma unroll
  for (int j = 0; j < 4; ++j)
    dst[(size_t)(drow + ty * 4 + j) * 1024 + k0 + tx] = f2bf(tile[tx][ty * 4 + j]);
}

// ---------------- bf16 MFMA GEMM, LDS double-buffered (T3 min-2-phase) ------
template <int BM, bool BF16_OUT>
__global__ __launch_bounds__(512) void gemm_bf16_k(
    const u16* __restrict__ A, const u16* __restrict__ Bt, void* __restrict__ Cv,
    int M, int N, int K) {
  constexpr int MI = BM / 32;
  __shared__ __align__(16) u16 As[2][BM * 64];
  __shared__ __align__(16) u16 Bs[2][128 * 64];
  int tid = threadIdx.x;
  int w = tid >> 6, l = tid & 63;
  int wr = w >> 2, wc = w & 3;
  int lr = l & 15, lg = l >> 4;
  int lrow = l >> 3, lcol = (l & 7) * 8;  // staging decomposition
  int m0 = blockIdx.y * BM, n0 = blockIdx.x * 128;
  f32x4 zero = {0.f, 0.f, 0.f, 0.f};
  f32x4 acc[MI][2];
#pragma unroll
  for (int mi = 0; mi < MI; ++mi)
#pragma unroll
    for (int ni = 0; ni < 2; ++ni) acc[mi][ni] = zero;

  auto gstage = [&](int buf, int kt) {
#pragma unroll
    for (int ts = 0; ts < BM / 64; ++ts) {
      int seg = ts * 8 + w;
      gll16(&A[(size_t)(m0 + seg * 8 + lrow) * K + kt + lcol],
            &As[buf][seg * 512]);
    }
#pragma unroll
    for (int ts = 0; ts < 2; ++ts) {
      int seg = ts * 8 + w;
      gll16(&Bt[(size_t)(n0 + seg * 8 + lrow) * K + kt + lcol],
            &Bs[buf][seg * 512]);
    }
  };

  gstage(0, 0);
  __syncthreads();
  int nt = K >> 6;
#pragma unroll 1
  for (int t = 0; t < nt; ++t) {
    int cur = t & 1;
    if (t + 1 < nt) gstage(cur ^ 1, (t + 1) * 64);
#pragma unroll
    for (int kw = 0; kw < 2; ++kw) {
      bf16x8 af[MI], bfr[2];
#pragma unroll
      for (int mi = 0; mi < MI; ++mi)
        af[mi] = *(const bf16x8*)&As[cur][(wr * (BM / 2) + mi * 16 + lr) * 64 + kw * 32 + lg * 8];
#pragma unroll
      for (int ni = 0; ni < 2; ++ni)
        bfr[ni] = *(const bf16x8*)&Bs[cur][(wc * 32 + ni * 16 + lr) * 64 + kw * 32 + lg * 8];
#pragma unroll
      for (int mi = 0; mi < MI; ++mi)
#pragma unroll
        for (int ni = 0; ni < 2; ++ni)
          acc[mi][ni] = __builtin_amdgcn_mfma_f32_16x16x32_bf16(
              af[mi], bfr[ni], acc[mi][ni], 0, 0, 0);
    }
    __syncthreads();  // single barrier: readers done + next-buf loads drained
  }
#pragma unroll
  for (int mi = 0; mi < MI; ++mi)
#pragma unroll
    for (int ni = 0; ni < 2; ++ni)
#pragma unroll
      for (int r = 0; r < 4; ++r) {
        int row = m0 + wr * (BM / 2) + mi * 16 + lg * 4 + r;
        int col = n0 + wc * 32 + ni * 16 + lr;
        if (BF16_OUT)
          ((u16*)Cv)[(size_t)row * N + col] = f2bf(acc[mi][ni][r]);
        else
          ((float*)Cv)[(size_t)row * N + col] = acc[mi][ni][r];
      }
}

// ---------------- postprocess: g/m sigmoid, v-mix, k RMS+RoPE only ----------
// (q RoPE moved into attn's fragment load -- q is read exactly once there)
__global__ __launch_bounds__(256) void postproc_k(
    const float* __restrict__ bm, const float* __restrict__ ksc,
    const float* __restrict__ rtab, u16* __restrict__ qkvrb,
    u16* __restrict__ kb, u16* __restrict__ vb, float* __restrict__ g_out) {
  int s = blockIdx.x, tid = threadIdx.x;
  int lane = tid & 63, w = tid >> 6;
  u16* row = qkvrb + (size_t)s * 1920;
  const float* tr = rtab + (size_t)s * 64;
  if (tid < 16)
    g_out[s * 16 + tid] = 1.f / (1.f + __expf(-bf2f(row[1792 + tid])));
  int h = w, d = lane;
  float c = tr[d >> 1], sn = tr[32 + (d >> 1)];
  {  // v mix -> vb [h][s][d]
    float mixv = 1.f / (1.f + __expf(-(bf2f(row[1808 + h]) + bm[h])));
    float vv = bf2f(row[1280 + h * 64 + d]);
    float rv = bf2f(row[1536 + h * 64 + d]);
    vb[((size_t)h * 2048 + s) * 64 + d] = f2bf(vv + mixv * (rv - vv));
  }
  {  // k: RMSNorm * k_scale + RoPE -> kb [h][s][d]
    float kv = bf2f(row[1024 + h * 64 + d]);
    float ss = kv * kv;
#pragma unroll
    for (int off = 32; off > 0; off >>= 1) ss += __shfl_xor(ss, off);
    float rms = sqrtf(ss * (1.f / 64.f) + 1e-8f);
    float kn = kv / rms * ksc[h * 64 + d];
    float partner = __shfl_xor(kn, 1);
    kb[((size_t)h * 2048 + s) * 64 + d] =
        f2bf((d & 1) ? fmaf(kn, c, partner * sn) : fmaf(kn, c, -partner * sn));
  }
}

// ---------------- vb [h][s][d] -> vtb [h][d][s] -----------------------------
#define TPAD 66
__global__ __launch_bounds__(256) void vtrans_k(const u16* __restrict__ vb,
                                               u16* __restrict__ vtb) {
  __shared__ u16 tile[64 * TPAD];
  int h = blockIdx.y, s0 = blockIdx.x * 64;
  int t = threadIdx.x;
  {
    int r = t >> 2, cb = (t & 3) * 16;
    const u16* src = vb + ((size_t)h * 2048 + s0 + r) * 64 + cb;
    *(uint4*)&tile[r * TPAD + cb] = *(const uint4*)src;
    *(uint4*)&tile[r * TPAD + cb + 8] = *(const uint4*)(src + 8);
  }
  __syncthreads();
  int d = t >> 2, sb = (t & 3) * 16;
  u16 vals[16];
#pragma unroll
  for (int j = 0; j < 16; ++j) vals[j] = tile[(sb + j) * TPAD + d];
  uint4 a, b;
  a.x = (u32)vals[0] | ((u32)vals[1] << 16);
  a.y = (u32)vals[2] | ((u32)vals[3] << 16);
  a.z = (u32)vals[4] | ((u32)vals[5] << 16);
  a.w = (u32)vals[6] | ((u32)vals[7] << 16);
  b.x = (u32)vals[8] | ((u32)vals[9] << 16);
  b.y = (u32)vals[10] | ((u32)vals[11] << 16);
  b.z = (u32)vals[12] | ((u32)vals[13] << 16);
  b.w = (u32)vals[14] | ((u32)vals[15] << 16);
  u16* dst = vtb + ((size_t)h * 64 + d) * 2048 + s0 + sb;
  *(uint4*)dst = a;
  *(uint4*)(dst + 8) = b;
}

// ---------------- MFMA causal attention: fused q-RoPE fragment load ---------
// Round-22 structure (triple-buf, counted vmcnt, poly softclamp, LDS-P) +
// q RoPE applied IN-REGISTER at fragment build: frag holds 8 consecutive d,
// so rotate-half pairs are register-adjacent; cos/sin = 2 float4 from rtab.
__global__ __launch_bounds__(512) void attn_k(
    const u16* __restrict__ qkvrb, const u16* __restrict__ kb,
    const u16* __restrict__ vtb, const float* __restrict__ g,
    const float* __restrict__ rtab, u16* __restrict__ aob) {
  __shared__ __align__(16) u16 smem[57344];  // 112KB: 2grp x 3buf x 8KB + 16KB Pw
  int head = blockIdx.x, hkv = head >> 2;
  int tid = threadIdx.x;
  int w = tid >> 6, l = tid & 63;
  int grp = w >> 2, wi = w & 3;
  int lr = l & 15, lg = l >> 4;
  int gtid = wi * 64 + l;
  u16* KsBase = smem + grp * 24576;  // buf b at +b*8192; Vt = Ks + 4096
  u32* pw = (u32*)(smem + 49152) + (size_t)w * 512;  // per-wave 16 x 32 u32
  float* mbuf = (float*)smem;        // merge: 256 x 17 f32 (17.4 KB, aliases)
  f32x4 zero = {0.f, 0.f, 0.f, 0.f};
  const float L2E = 1.4426950408889634f;   // log2(e)
  const float NB = -72.13475204444817f;    // -50 * log2(e)
  int sw = (lr & 7) << 2;                  // P-tile column swizzle
  int u0 = ((lg ^ (lr & 7)) << 3);         // K/V physical u16 offset of unit
  int srow = l >> 3;
  int sunit = (l & 7) ^ srow;
  const u16* ksrc = kb + ((size_t)hkv * 2048 + srow) * 64 + sunit * 8;
  const u16* vsrc = vtb + ((size_t)(hkv * 64 + srow)) * 2048 + sunit * 8;
  auto stageChunk = [&](int b, int cc) {  // 4 gll16 per thread, uniform
    u16* Kb = KsBase + b * 8192;
#pragma unroll
    for (int t = 0; t < 2; ++t) {
      int seg = wi * 2 + t;
      gll16(ksrc + (size_t)(cc * 64 + seg * 8) * 64, Kb + seg * 512);
      gll16(vsrc + (size_t)(seg * 8) * 2048 + cc * 64, Kb + 4096 + seg * 512);
    }
  };
#pragma unroll 1
  for (int half = 0; half < 2; ++half) {
    int rb = half ? (int)blockIdx.y : (31 - (int)blockIdx.y);
    int row0 = rb * 64;
    int qglob = row0 + wi * 16 + lr;
    // ---- q fragment build with in-register RoPE + 0.125 scale ----
    const u16* qrow = qkvrb + (size_t)qglob * 1920 + head * 64;
    const float* trq = rtab + (size_t)qglob * 64;
    bf16x8 qf0, qf1;
    {
      float ce0[4], se0[4], ce1[4], se1[4];
      *(float4*)ce0 = *(const float4*)&trq[lg * 4];
      *(float4*)se0 = *(const float4*)&trq[32 + lg * 4];
      *(float4*)ce1 = *(const float4*)&trq[16 + lg * 4];
      *(float4*)se1 = *(const float4*)&trq[48 + lg * 4];
      uint4 qr0 = *(const uint4*)&qrow[lg * 8];
      uint4 qr1 = *(const uint4*)&qrow[32 + lg * 8];
      const u16* qp0 = (const u16*)&qr0;
      const u16* qp1 = (const u16*)&qr1;
      union { u32 w[4]; bf16x8 v; } b0, b1;
#pragma unroll
      for (int j = 0; j < 4; ++j) {
        float e0 = bf2f(qp0[2 * j]), e1 = bf2f(qp0[2 * j + 1]);
        float r0 = (e0 * ce0[j] - e1 * se0[j]) * 0.125f;
        float r1 = (e1 * ce0[j] + e0 * se0[j]) * 0.125f;
        b0.w[j] = (u32)f2bf(r0) | ((u32)f2bf(r1) << 16);
        float f0 = bf2f(qp1[2 * j]), f1 = bf2f(qp1[2 * j + 1]);
        float t0 = (f0 * ce1[j] - f1 * se1[j]) * 0.125f;
        float t1 = (f1 * ce1[j] + f0 * se1[j]) * 0.125f;
        b1.w[j] = (u32)f2bf(t0) | ((u32)f2bf(t1) << 16);
      }
      qf0 = b0.v;
      qf1 = b1.v;
    }
    f32x4 acc_o[4];
#pragma unroll
    for (int nd = 0; nd < 4; ++nd) acc_o[nd] = zero;
    float l_part = 0.f;
    int c = grp;
    // prologue: stage c -> buf0, c+2 -> buf1; wait for buf0 only
    if (c <= rb) stageChunk(0, c);
    if (c + 2 <= rb) {
      stageChunk(1, c + 2);
      asm volatile("s_waitcnt vmcnt(4)\n\ts_barrier" ::: "memory");
    } else {
      asm volatile("s_waitcnt vmcnt(0)\n\ts_barrier" ::: "memory");
    }
    int nmax = (rb >> 1) + 1;
    int bufc = 0;
#pragma unroll 1
    for (int i = 0; i < nmax; ++i, c += 2) {
      bool valid = (c <= rb);
      bool sn = (c + 4 <= rb);
      if (sn) {  // stage c+4 into buf (bufc+2)%3
        int bufs = bufc - 1;
        if (bufs < 0) bufs = 2;
        stageChunk(bufs, c + 4);
      }
      if (valid) {
        u16* Ks = KsBase + bufc * 8192;
        u16* Vt = Ks + 4096;
        int kbase = c * 64;
        __builtin_amdgcn_s_setprio(1);
        // swapped QK^T: A=K (row=key, k=d), B=q (col=q) -> D[key][q]
        f32x4 sa[4];
#pragma unroll
        for (int ni = 0; ni < 4; ++ni) {
          const u16* kp = &Ks[(ni * 16 + lr) * 64];
          bf16x8 a0 = *(const bf16x8*)&kp[u0];
          bf16x8 a1 = *(const bf16x8*)&kp[u0 ^ 32];
          f32x4 t = __builtin_amdgcn_mfma_f32_16x16x32_bf16(a0, qf0, zero, 0, 0, 0);
          sa[ni] = __builtin_amdgcn_mfma_f32_16x16x32_bf16(a1, qf1, t, 0, 0, 0);
        }
        bool diag = (c == rb);
        // p = exp(50*tanh(s/50)-50) via Taylor poly (1 exp2, no rcp)
#pragma unroll
        for (int ni = 0; ni < 4; ++ni) {
          float pv[4];
#pragma unroll
          for (int r = 0; r < 4; ++r) {
            float sv = fminf(fmaxf(sa[ni][r], -60.f), 60.f);
            float t2 = sv * 0.02f;
            float u = t2 * t2;
            float cl = sv * fmaf(u, fmaf(u, 0.13333333f, -0.33333333f), 1.f);
            float p = __builtin_amdgcn_exp2f(fmaf(cl, L2E, NB));
            if (diag && (kbase + ni * 16 + lg * 4 + r) > qglob) p = 0.f;
            pv[r] = p;
            l_part += p;
          }
          u32 w0, w1;
          asm("v_cvt_pk_bf16_f32 %0, %1, %2" : "=v"(w0) : "v"(pv[0]), "v"(pv[1]));
          asm("v_cvt_pk_bf16_f32 %0, %1, %2" : "=v"(w1) : "v"(pv[2]), "v"(pv[3]));
          uint2 pr;
          pr.x = w0;
          pr.y = w1;
          *(uint2*)&pw[lr * 32 + ((ni * 8 + lg * 2) ^ sw)] = pr;
        }
        // read PV A-fragments back (wave-internal LDS: in-order, no barrier)
        bf16x8 pfa = *(const bf16x8*)&pw[lr * 32 + ((lg * 4) ^ sw)];
        bf16x8 pfb = *(const bf16x8*)&pw[lr * 32 + ((16 + lg * 4) ^ sw)];
        // PV: A=P (row=q, k=key), B=V^T (col=d, k=key)
#pragma unroll
        for (int nd = 0; nd < 4; ++nd) {
          const u16* vp = &Vt[(nd * 16 + lr) * 64];
          bf16x8 v0 = *(const bf16x8*)&vp[u0];
          bf16x8 v1 = *(const bf16x8*)&vp[u0 ^ 32];
          acc_o[nd] = __builtin_amdgcn_mfma_f32_16x16x32_bf16(pfa, v0, acc_o[nd], 0, 0, 0);
          acc_o[nd] = __builtin_amdgcn_mfma_f32_16x16x32_bf16(pfb, v1, acc_o[nd], 0, 0, 0);
        }
        __builtin_amdgcn_s_setprio(0);
      }
      // counted-vmcnt barrier: keep this iter's stage in flight (T4)
      if (sn) {
        asm volatile("s_waitcnt vmcnt(4)\n\ts_barrier" ::: "memory");
      } else {
        asm volatile("s_waitcnt vmcnt(0)\n\ts_barrier" ::: "memory");
      }
      bufc = (bufc == 2) ? 0 : bufc + 1;
    }
    // reduce l within wave (sum 4 lg copies of each q-row)
    l_part += __shfl_xor(l_part, 16);
    l_part += __shfl_xor(l_part, 32);
    // merge groups via LDS (buffers dead after final loop barrier)
    if (grp == 1) {
      float* mb = mbuf + (size_t)gtid * 17;
#pragma unroll
      for (int nd = 0; nd < 4; ++nd)
#pragma unroll
        for (int r = 0; r < 4; ++r) mb[nd * 4 + r] = acc_o[nd][r];
      mb[16] = l_part;
    }
    __syncthreads();
    if (grp == 0) {
      const float* mb = mbuf + (size_t)gtid * 17;
      float lt = l_part + mb[16];
#pragma unroll
      for (int r = 0; r < 4; ++r) {
        int row = row0 + wi * 16 + lg * 4 + r;
        float lv = __shfl(lt, lg * 4 + r);
        float sc = g[row * 16 + head] * __builtin_amdgcn_rcpf(lv);
#pragma unroll
        for (int nd = 0; nd < 4; ++nd)
          aob[(size_t)row * 1024 + head * 64 + nd * 16 + lr] =
              f2bf((acc_o[nd][r] + mb[nd * 4 + r]) * sc);
      }
    }
    __syncthreads();  // mbuf reads done before next half restages buffers
  }
}

extern "C" void kernel_launch(void* const* d_in, const int* in_sizes, int n_in,
                              void* d_out, int out_size, void* d_ws,
                              size_t ws_size, hipStream_t stream) {
  const float* x = (const float*)d_in[0];
  const int* positions = (const int*)d_in[1];
  const float* Wq = (const float*)d_in[3];
  const float* Wk = (const float*)d_in[4];
  const float* Wv = (const float*)d_in[5];
  const float* Wo = (const float*)d_in[6];
  const float* Wg = (const float*)d_in[7];
  const float* Wm = (const float*)d_in[8];
  const float* bm = (const float*)d_in[9];
  const float* Wvr = (const float*)d_in[10];
  const float* ksc = (const float*)d_in[11];
  float* out = (float*)d_out;

  u16* xb = (u16*)d_ws;                            // 2048*1024
  u16* WallT = xb + (size_t)2048 * 1024;           // 1920*1024
  u16* WoT = WallT + (size_t)1920 * 1024;          // 1024*1024
  u16* qkvrb = WoT + (size_t)1024 * 1024;          // 2048*1920
  u16* kbuf = qkvrb + (size_t)2048 * 1920;         // 4*2048*64
  u16* vbuf = kbuf + (size_t)4 * 2048 * 64;
  u16* vtb = vbuf + (size_t)4 * 2048 * 64;
  float* gbuf = (float*)(vtb + (size_t)4 * 2048 * 64);  // 2048*16 f32
  float* rtab = gbuf + (size_t)2048 * 16;               // 2048*64 f32
  u16* aob = xb;  // xb dead after gemm1

  prep_all_k<<<4224, 256, 0, stream>>>(x, positions, Wq, Wk, Wv, Wvr, Wo, Wg,
                                       Wm, xb, WallT, WoT, rtab);
  gemm_bf16_k<128, true><<<dim3(15, 16), 512, 0, stream>>>(xb, WallT, qkvrb,
                                                           2048, 1920, 1024);
  postproc_k<<<2048, 256, 0, stream>>>(bm, ksc, rtab, qkvrb, kbuf, vbuf, gbuf);
  vtrans_k<<<dim3(32, 4), 256, 0, stream>>>(vbuf, vtb);
  attn_k<<<dim3(16, 16), 512, 0, stream>>>(qkvrb, kbuf, vtb, gbuf, rtab, aob);
  gemm_bf16_k<64, false><<<dim3(8, 32), 512, 0, stream>>>(aob, WoT, out, 2048,
                                                          1024, 1024);
}

// Round 24
// 88.383 us; speedup vs baseline: 1.0164x; 1.0164x over previous
//
#include <hip/hip_runtime.h>
#include <hip/hip_bf16.h>
#include <math.h>

typedef unsigned short u16;
typedef unsigned int u32;
typedef __attribute__((ext_vector_type(8))) __bf16 bf16x8;
typedef __attribute__((ext_vector_type(4))) float f32x4;

__device__ inline u16 f2bf(float f) {
  u32 b = __float_as_uint(f);
  b += 0x7FFFu + ((b >> 16) & 1u);
  return (u16)(b >> 16);
}
__device__ inline float bf2f(u16 b) { return __uint_as_float((u32)b << 16); }

// async global->LDS, 16 bytes per lane; LDS dest = uniform base + lane*16
__device__ __forceinline__ void gll16(const void* gp, void* lp) {
  __builtin_amdgcn_global_load_lds(
      (const __attribute__((address_space(1))) void*)gp,
      (__attribute__((address_space(3))) void*)lp, 16, 0, 0);
}

// ---------------- fused prep: cvt | weight transposes | rope table ----------
// grid 4224 x 256: [0,1024) cvt x->xb ; [1024,3968) prep_w ; [3968,4224) rope
__global__ __launch_bounds__(256) void prep_all_k(
    const float* __restrict__ x, const int* __restrict__ positions,
    const float* __restrict__ Wq, const float* __restrict__ Wk,
    const float* __restrict__ Wv, const float* __restrict__ Wvr,
    const float* __restrict__ Wo, const float* __restrict__ Wg,
    const float* __restrict__ Wm, u16* __restrict__ xb,
    u16* __restrict__ WallT, u16* __restrict__ WoT, float* __restrict__ rtab) {
  __shared__ float tile[32][33];
  int bid = blockIdx.x, tid = threadIdx.x;
  if (bid < 1024) {  // ---- cvt ----
    int i = (bid * 256 + tid) * 8;
    float4 v0 = *(const float4*)&x[i];
    float4 v1 = *(const float4*)&x[i + 4];
    uint4 pk;
    pk.x = (u32)f2bf(v0.x) | ((u32)f2bf(v0.y) << 16);
    pk.y = (u32)f2bf(v0.z) | ((u32)f2bf(v0.w) << 16);
    pk.z = (u32)f2bf(v1.x) | ((u32)f2bf(v1.y) << 16);
    pk.w = (u32)f2bf(v1.z) | ((u32)f2bf(v1.w) << 16);
    *(uint4*)&xb[i] = pk;
    return;
  }
  if (bid >= 3968) {  // ---- rope table ----
    int idx = (bid - 3968) * 256 + tid;
    int s = idx >> 5, f = idx & 31;
    float inv = __expf(-(float)f * (9.210340371976184f / 32.f));
    float ang = (float)positions[s] * inv;
    rtab[(size_t)s * 64 + f] = cosf(ang);
    rtab[(size_t)s * 64 + 32 + f] = sinf(ang);
    return;
  }
  // ---- weight prep ----
  int b2 = bid - 1024;
  int k0 = (b2 & 31) * 32;
  int ybl = b2 >> 5;
  int tx = tid & 31, ty = tid >> 5;
  const float* src;
  int scol, sN, drow;
  u16* dst;
  if (ybl >= 60) {
    src = Wo; scol = (ybl - 60) * 32; sN = 1024; dst = WoT; drow = scol;
  } else {
    int n0 = ybl * 32;
    if (n0 >= 1792) {  // Wg/Wm/zero region, direct (no LDS)
#pragma unroll
      for (int j = 0; j < 4; ++j) {
        int n = n0 + ty * 4 + j, j2 = n - 1792, k = k0 + tx;
        float val = (j2 < 16) ? Wg[(size_t)k * 16 + j2]
                  : (j2 < 20) ? Wm[(size_t)k * 4 + (j2 - 16)] : 0.f;
        WallT[(size_t)n * 1024 + k] = f2bf(val);
      }
      return;
    }
    dst = WallT; drow = n0;
    if (n0 < 1024) { src = Wq; scol = n0; sN = 1024; }
    else if (n0 < 1280) { src = Wk; scol = n0 - 1024; sN = 256; }
    else if (n0 < 1536) { src = Wv; scol = n0 - 1280; sN = 256; }
    else { src = Wvr; scol = n0 - 1536; sN = 256; }
  }
#pragma unroll
  for (int j = 0; j < 4; ++j)
    tile[ty * 4 + j][tx] = src[(size_t)(k0 + ty * 4 + j) * sN + scol + tx];
  __syncthreads();
#pragma unroll
  for (int j = 0; j < 4; ++j)
    dst[(size_t)(drow + ty * 4 + j) * 1024 + k0 + tx] = f2bf(tile[tx][ty * 4 + j]);
}

// ---------------- bf16 MFMA GEMM, LDS double-buffered (T3 min-2-phase) ------
template <int BM, bool BF16_OUT>
__global__ __launch_bounds__(512) void gemm_bf16_k(
    const u16* __restrict__ A, const u16* __restrict__ Bt, void* __restrict__ Cv,
    int M, int N, int K) {
  constexpr int MI = BM / 32;
  __shared__ __align__(16) u16 As[2][BM * 64];
  __shared__ __align__(16) u16 Bs[2][128 * 64];
  int tid = threadIdx.x;
  int w = tid >> 6, l = tid & 63;
  int wr = w >> 2, wc = w & 3;
  int lr = l & 15, lg = l >> 4;
  int lrow = l >> 3, lcol = (l & 7) * 8;  // staging decomposition
  int m0 = blockIdx.y * BM, n0 = blockIdx.x * 128;
  f32x4 zero = {0.f, 0.f, 0.f, 0.f};
  f32x4 acc[MI][2];
#pragma unroll
  for (int mi = 0; mi < MI; ++mi)
#pragma unroll
    for (int ni = 0; ni < 2; ++ni) acc[mi][ni] = zero;

  auto gstage = [&](int buf, int kt) {
#pragma unroll
    for (int ts = 0; ts < BM / 64; ++ts) {
      int seg = ts * 8 + w;
      gll16(&A[(size_t)(m0 + seg * 8 + lrow) * K + kt + lcol],
            &As[buf][seg * 512]);
    }
#pragma unroll
    for (int ts = 0; ts < 2; ++ts) {
      int seg = ts * 8 + w;
      gll16(&Bt[(size_t)(n0 + seg * 8 + lrow) * K + kt + lcol],
            &Bs[buf][seg * 512]);
    }
  };

  gstage(0, 0);
  __syncthreads();
  int nt = K >> 6;
#pragma unroll 1
  for (int t = 0; t < nt; ++t) {
    int cur = t & 1;
    if (t + 1 < nt) gstage(cur ^ 1, (t + 1) * 64);
#pragma unroll
    for (int kw = 0; kw < 2; ++kw) {
      bf16x8 af[MI], bfr[2];
#pragma unroll
      for (int mi = 0; mi < MI; ++mi)
        af[mi] = *(const bf16x8*)&As[cur][(wr * (BM / 2) + mi * 16 + lr) * 64 + kw * 32 + lg * 8];
#pragma unroll
      for (int ni = 0; ni < 2; ++ni)
        bfr[ni] = *(const bf16x8*)&Bs[cur][(wc * 32 + ni * 16 + lr) * 64 + kw * 32 + lg * 8];
#pragma unroll
      for (int mi = 0; mi < MI; ++mi)
#pragma unroll
        for (int ni = 0; ni < 2; ++ni)
          acc[mi][ni] = __builtin_amdgcn_mfma_f32_16x16x32_bf16(
              af[mi], bfr[ni], acc[mi][ni], 0, 0, 0);
    }
    __syncthreads();  // single barrier: readers done + next-buf loads drained
  }
#pragma unroll
  for (int mi = 0; mi < MI; ++mi)
#pragma unroll
    for (int ni = 0; ni < 2; ++ni)
#pragma unroll
      for (int r = 0; r < 4; ++r) {
        int row = m0 + wr * (BM / 2) + mi * 16 + lg * 4 + r;
        int col = n0 + wc * 32 + ni * 16 + lr;
        if (BF16_OUT)
          ((u16*)Cv)[(size_t)row * N + col] = f2bf(acc[mi][ni][r]);
        else
          ((float*)Cv)[(size_t)row * N + col] = acc[mi][ni][r];
      }
}

// ---------------- fused postprocess + v transpose ---------------------------
// grid (32 s-tiles, 4 kv-heads), 256 thr. Per block: 64 s rows x 64 d.
// Thread = 4 per row (sl = t>>2), 16 contiguous d each (db = (t&3)*16).
// k: RMS (4-lane shfl reduce) * k_scale + RoPE (pairs register-adjacent),
// coalesced kb write. v: sigmoid-mix -> LDS tile -> transpose-write vtb.
// g sigmoids done by h==0 blocks. vbuf intermediate eliminated.
#define TPAD 66
__global__ __launch_bounds__(256) void postv_k(
    const float* __restrict__ bm, const float* __restrict__ ksc,
    const float* __restrict__ rtab, const u16* __restrict__ qkvrb,
    u16* __restrict__ kb, u16* __restrict__ vtb, float* __restrict__ g_out) {
  __shared__ u16 tile[64 * TPAD];
  int s0 = blockIdx.x * 64, h = blockIdx.y;
  int t = threadIdx.x;
  int sl = t >> 2, db = (t & 3) * 16;
  int s = s0 + sl;
  const u16* row = qkvrb + (size_t)s * 1920;
  if (h == 0) {  // g sigmoids for this s-tile (16 heads x 64 rows)
#pragma unroll
    for (int j = 0; j < 4; ++j) {
      int idx = j * 256 + t;
      int sg = s0 + (idx >> 4), hh = idx & 15;
      g_out[sg * 16 + hh] =
          1.f / (1.f + __expf(-bf2f(qkvrb[(size_t)sg * 1920 + 1792 + hh])));
    }
  }
  // ---- k: RMSNorm * k_scale + RoPE -> kb [h][s][d] ----
  float kvv[16];
  float ssq = 0.f;
  {
    uint4 kr0 = *(const uint4*)&row[1024 + h * 64 + db];
    uint4 kr1 = *(const uint4*)&row[1024 + h * 64 + db + 8];
    const u16* p0 = (const u16*)&kr0;
    const u16* p1 = (const u16*)&kr1;
#pragma unroll
    for (int j = 0; j < 8; ++j) {
      kvv[j] = bf2f(p0[j]);
      ssq += kvv[j] * kvv[j];
    }
#pragma unroll
    for (int j = 0; j < 8; ++j) {
      kvv[8 + j] = bf2f(p1[j]);
      ssq += kvv[8 + j] * kvv[8 + j];
    }
  }
  ssq += __shfl_xor(ssq, 1);
  ssq += __shfl_xor(ssq, 2);
  float rinv = 1.f / sqrtf(ssq * (1.f / 64.f) + 1e-8f);
  const float* tr = rtab + (size_t)s * 64;
  float cs[8], sn[8];
  *(float4*)cs = *(const float4*)&tr[db >> 1];
  *(float4*)(cs + 4) = *(const float4*)&tr[(db >> 1) + 4];
  *(float4*)sn = *(const float4*)&tr[32 + (db >> 1)];
  *(float4*)(sn + 4) = *(const float4*)&tr[32 + (db >> 1) + 4];
  float scl[16];
  *(float4*)scl = *(const float4*)&ksc[h * 64 + db];
  *(float4*)(scl + 4) = *(const float4*)&ksc[h * 64 + db + 4];
  *(float4*)(scl + 8) = *(const float4*)&ksc[h * 64 + db + 8];
  *(float4*)(scl + 12) = *(const float4*)&ksc[h * 64 + db + 12];
  {
    u16 outk[16];
#pragma unroll
    for (int j = 0; j < 8; ++j) {
      float e = kvv[2 * j] * rinv * scl[2 * j];
      float o = kvv[2 * j + 1] * rinv * scl[2 * j + 1];
      outk[2 * j] = f2bf(e * cs[j] - o * sn[j]);
      outk[2 * j + 1] = f2bf(o * cs[j] + e * sn[j]);
    }
    u16* kdst = kb + ((size_t)h * 2048 + s) * 64 + db;
    *(uint4*)kdst = *(uint4*)outk;
    *(uint4*)(kdst + 8) = *(uint4*)(outk + 8);
  }
  // ---- v: mix -> LDS tile ----
  {
    float mixv = 1.f / (1.f + __expf(-(bf2f(row[1808 + h]) + bm[h])));
    uint4 vr0 = *(const uint4*)&row[1280 + h * 64 + db];
    uint4 vr1 = *(const uint4*)&row[1280 + h * 64 + db + 8];
    uint4 rr0 = *(const uint4*)&row[1536 + h * 64 + db];
    uint4 rr1 = *(const uint4*)&row[1536 + h * 64 + db + 8];
    const u16* vp0 = (const u16*)&vr0;
    const u16* vp1 = (const u16*)&vr1;
    const u16* rp0 = (const u16*)&rr0;
    const u16* rp1 = (const u16*)&rr1;
#pragma unroll
    for (int j = 0; j < 8; ++j) {
      float vv = bf2f(vp0[j]);
      tile[sl * TPAD + db + j] = f2bf(vv + mixv * (bf2f(rp0[j]) - vv));
    }
#pragma unroll
    for (int j = 0; j < 8; ++j) {
      float vv = bf2f(vp1[j]);
      tile[sl * TPAD + db + 8 + j] = f2bf(vv + mixv * (bf2f(rp1[j]) - vv));
    }
  }
  __syncthreads();
  // ---- transpose-write vtb [h][d][s] (as old vtrans) ----
  {
    int d = t >> 2, sb = (t & 3) * 16;
    u16 vals[16];
#pragma unroll
    for (int j = 0; j < 16; ++j) vals[j] = tile[(sb + j) * TPAD + d];
    uint4 a, b;
    a.x = (u32)vals[0] | ((u32)vals[1] << 16);
    a.y = (u32)vals[2] | ((u32)vals[3] << 16);
    a.z = (u32)vals[4] | ((u32)vals[5] << 16);
    a.w = (u32)vals[6] | ((u32)vals[7] << 16);
    b.x = (u32)vals[8] | ((u32)vals[9] << 16);
    b.y = (u32)vals[10] | ((u32)vals[11] << 16);
    b.z = (u32)vals[12] | ((u32)vals[13] << 16);
    b.w = (u32)vals[14] | ((u32)vals[15] << 16);
    u16* dst = vtb + ((size_t)h * 64 + d) * 2048 + s0 + sb;
    *(uint4*)dst = a;
    *(uint4*)(dst + 8) = b;
  }
}

// ---------------- MFMA causal attention: fused q-RoPE fragment load ---------
// Triple-buf, counted vmcnt, poly softclamp, LDS-P; q RoPE in-register.
__global__ __launch_bounds__(512) void attn_k(
    const u16* __restrict__ qkvrb, const u16* __restrict__ kb,
    const u16* __restrict__ vtb, const float* __restrict__ g,
    const float* __restrict__ rtab, u16* __restrict__ aob) {
  __shared__ __align__(16) u16 smem[57344];  // 112KB: 2grp x 3buf x 8KB + 16KB Pw
  int head = blockIdx.x, hkv = head >> 2;
  int tid = threadIdx.x;
  int w = tid >> 6, l = tid & 63;
  int grp = w >> 2, wi = w & 3;
  int lr = l & 15, lg = l >> 4;
  int gtid = wi * 64 + l;
  u16* KsBase = smem + grp * 24576;  // buf b at +b*8192; Vt = Ks + 4096
  u32* pw = (u32*)(smem + 49152) + (size_t)w * 512;  // per-wave 16 x 32 u32
  float* mbuf = (float*)smem;        // merge: 256 x 17 f32 (17.4 KB, aliases)
  f32x4 zero = {0.f, 0.f, 0.f, 0.f};
  const float L2E = 1.4426950408889634f;   // log2(e)
  const float NB = -72.13475204444817f;    // -50 * log2(e)
  int sw = (lr & 7) << 2;                  // P-tile column swizzle
  int u0 = ((lg ^ (lr & 7)) << 3);         // K/V physical u16 offset of unit
  int srow = l >> 3;
  int sunit = (l & 7) ^ srow;
  const u16* ksrc = kb + ((size_t)hkv * 2048 + srow) * 64 + sunit * 8;
  const u16* vsrc = vtb + ((size_t)(hkv * 64 + srow)) * 2048 + sunit * 8;
  auto stageChunk = [&](int b, int cc) {  // 4 gll16 per thread, uniform
    u16* Kb = KsBase + b * 8192;
#pragma unroll
    for (int t = 0; t < 2; ++t) {
      int seg = wi * 2 + t;
      gll16(ksrc + (size_t)(cc * 64 + seg * 8) * 64, Kb + seg * 512);
      gll16(vsrc + (size_t)(seg * 8) * 2048 + cc * 64, Kb + 4096 + seg * 512);
    }
  };
#pragma unroll 1
  for (int half = 0; half < 2; ++half) {
    int rb = half ? (int)blockIdx.y : (31 - (int)blockIdx.y);
    int row0 = rb * 64;
    int qglob = row0 + wi * 16 + lr;
    // ---- q fragment build with in-register RoPE + 0.125 scale ----
    const u16* qrow = qkvrb + (size_t)qglob * 1920 + head * 64;
    const float* trq = rtab + (size_t)qglob * 64;
    bf16x8 qf0, qf1;
    {
      float ce0[4], se0[4], ce1[4], se1[4];
      *(float4*)ce0 = *(const float4*)&trq[lg * 4];
      *(float4*)se0 = *(const float4*)&trq[32 + lg * 4];
      *(float4*)ce1 = *(const float4*)&trq[16 + lg * 4];
      *(float4*)se1 = *(const float4*)&trq[48 + lg * 4];
      uint4 qr0 = *(const uint4*)&qrow[lg * 8];
      uint4 qr1 = *(const uint4*)&qrow[32 + lg * 8];
      const u16* qp0 = (const u16*)&qr0;
      const u16* qp1 = (const u16*)&qr1;
      union { u32 w[4]; bf16x8 v; } b0, b1;
#pragma unroll
      for (int j = 0; j < 4; ++j) {
        float e0 = bf2f(qp0[2 * j]), e1 = bf2f(qp0[2 * j + 1]);
        float r0 = (e0 * ce0[j] - e1 * se0[j]) * 0.125f;
        float r1 = (e1 * ce0[j] + e0 * se0[j]) * 0.125f;
        b0.w[j] = (u32)f2bf(r0) | ((u32)f2bf(r1) << 16);
        float f0 = bf2f(qp1[2 * j]), f1 = bf2f(qp1[2 * j + 1]);
        float t0 = (f0 * ce1[j] - f1 * se1[j]) * 0.125f;
        float t1 = (f1 * ce1[j] + f0 * se1[j]) * 0.125f;
        b1.w[j] = (u32)f2bf(t0) | ((u32)f2bf(t1) << 16);
      }
      qf0 = b0.v;
      qf1 = b1.v;
    }
    f32x4 acc_o[4];
#pragma unroll
    for (int nd = 0; nd < 4; ++nd) acc_o[nd] = zero;
    float l_part = 0.f;
    int c = grp;
    // prologue: stage c -> buf0, c+2 -> buf1; wait for buf0 only
    if (c <= rb) stageChunk(0, c);
    if (c + 2 <= rb) {
      stageChunk(1, c + 2);
      asm volatile("s_waitcnt vmcnt(4)\n\ts_barrier" ::: "memory");
    } else {
      asm volatile("s_waitcnt vmcnt(0)\n\ts_barrier" ::: "memory");
    }
    int nmax = (rb >> 1) + 1;
    int bufc = 0;
#pragma unroll 1
    for (int i = 0; i < nmax; ++i, c += 2) {
      bool valid = (c <= rb);
      bool sn = (c + 4 <= rb);
      if (sn) {  // stage c+4 into buf (bufc+2)%3
        int bufs = bufc - 1;
        if (bufs < 0) bufs = 2;
        stageChunk(bufs, c + 4);
      }
      if (valid) {
        u16* Ks = KsBase + bufc * 8192;
        u16* Vt = Ks + 4096;
        int kbase = c * 64;
        __builtin_amdgcn_s_setprio(1);
        // swapped QK^T: A=K (row=key, k=d), B=q (col=q) -> D[key][q]
        f32x4 sa[4];
#pragma unroll
        for (int ni = 0; ni < 4; ++ni) {
          const u16* kp = &Ks[(ni * 16 + lr) * 64];
          bf16x8 a0 = *(const bf16x8*)&kp[u0];
          bf16x8 a1 = *(const bf16x8*)&kp[u0 ^ 32];
          f32x4 t = __builtin_amdgcn_mfma_f32_16x16x32_bf16(a0, qf0, zero, 0, 0, 0);
          sa[ni] = __builtin_amdgcn_mfma_f32_16x16x32_bf16(a1, qf1, t, 0, 0, 0);
        }
        bool diag = (c == rb);
        // p = exp(50*tanh(s/50)-50) via Taylor poly (1 exp2, no rcp)
#pragma unroll
        for (int ni = 0; ni < 4; ++ni) {
          float pv[4];
#pragma unroll
          for (int r = 0; r < 4; ++r) {
            float sv = fminf(fmaxf(sa[ni][r], -60.f), 60.f);
            float t2 = sv * 0.02f;
            float u = t2 * t2;
            float cl = sv * fmaf(u, fmaf(u, 0.13333333f, -0.33333333f), 1.f);
            float p = __builtin_amdgcn_exp2f(fmaf(cl, L2E, NB));
            if (diag && (kbase + ni * 16 + lg * 4 + r) > qglob) p = 0.f;
            pv[r] = p;
            l_part += p;
          }
          u32 w0, w1;
          asm("v_cvt_pk_bf16_f32 %0, %1, %2" : "=v"(w0) : "v"(pv[0]), "v"(pv[1]));
          asm("v_cvt_pk_bf16_f32 %0, %1, %2" : "=v"(w1) : "v"(pv[2]), "v"(pv[3]));
          uint2 pr;
          pr.x = w0;
          pr.y = w1;
          *(uint2*)&pw[lr * 32 + ((ni * 8 + lg * 2) ^ sw)] = pr;
        }
        // read PV A-fragments back (wave-internal LDS: in-order, no barrier)
        bf16x8 pfa = *(const bf16x8*)&pw[lr * 32 + ((lg * 4) ^ sw)];
        bf16x8 pfb = *(const bf16x8*)&pw[lr * 32 + ((16 + lg * 4) ^ sw)];
        // PV: A=P (row=q, k=key), B=V^T (col=d, k=key)
#pragma unroll
        for (int nd = 0; nd < 4; ++nd) {
          const u16* vp = &Vt[(nd * 16 + lr) * 64];
          bf16x8 v0 = *(const bf16x8*)&vp[u0];
          bf16x8 v1 = *(const bf16x8*)&vp[u0 ^ 32];
          acc_o[nd] = __builtin_amdgcn_mfma_f32_16x16x32_bf16(pfa, v0, acc_o[nd], 0, 0, 0);
          acc_o[nd] = __builtin_amdgcn_mfma_f32_16x16x32_bf16(pfb, v1, acc_o[nd], 0, 0, 0);
        }
        __builtin_amdgcn_s_setprio(0);
      }
      // counted-vmcnt barrier: keep this iter's stage in flight (T4)
      if (sn) {
        asm volatile("s_waitcnt vmcnt(4)\n\ts_barrier" ::: "memory");
      } else {
        asm volatile("s_waitcnt vmcnt(0)\n\ts_barrier" ::: "memory");
      }
      bufc = (bufc == 2) ? 0 : bufc + 1;
    }
    // reduce l within wave (sum 4 lg copies of each q-row)
    l_part += __shfl_xor(l_part, 16);
    l_part += __shfl_xor(l_part, 32);
    // merge groups via LDS (buffers dead after final loop barrier)
    if (grp == 1) {
      float* mb = mbuf + (size_t)gtid * 17;
#pragma unroll
      for (int nd = 0; nd < 4; ++nd)
#pragma unroll
        for (int r = 0; r < 4; ++r) mb[nd * 4 + r] = acc_o[nd][r];
      mb[16] = l_part;
    }
    __syncthreads();
    if (grp == 0) {
      const float* mb = mbuf + (size_t)gtid * 17;
      float lt = l_part + mb[16];
#pragma unroll
      for (int r = 0; r < 4; ++r) {
        int row = row0 + wi * 16 + lg * 4 + r;
        float lv = __shfl(lt, lg * 4 + r);
        float sc = g[row * 16 + head] * __builtin_amdgcn_rcpf(lv);
#pragma unroll
        for (int nd = 0; nd < 4; ++nd)
          aob[(size_t)row * 1024 + head * 64 + nd * 16 + lr] =
              f2bf((acc_o[nd][r] + mb[nd * 4 + r]) * sc);
      }
    }
    __syncthreads();  // mbuf reads done before next half restages buffers
  }
}

extern "C" void kernel_launch(void* const* d_in, const int* in_sizes, int n_in,
                              void* d_out, int out_size, void* d_ws,
                              size_t ws_size, hipStream_t stream) {
  const float* x = (const float*)d_in[0];
  const int* positions = (const int*)d_in[1];
  const float* Wq = (const float*)d_in[3];
  const float* Wk = (const float*)d_in[4];
  const float* Wv = (const float*)d_in[5];
  const float* Wo = (const float*)d_in[6];
  const float* Wg = (const float*)d_in[7];
  const float* Wm = (const float*)d_in[8];
  const float* bm = (const float*)d_in[9];
  const float* Wvr = (const float*)d_in[10];
  const float* ksc = (const float*)d_in[11];
  float* out = (float*)d_out;

  u16* xb = (u16*)d_ws;                            // 2048*1024
  u16* WallT = xb + (size_t)2048 * 1024;           // 1920*1024
  u16* WoT = WallT + (size_t)1920 * 1024;          // 1024*1024
  u16* qkvrb = WoT + (size_t)1024 * 1024;          // 2048*1920
  u16* kbuf = qkvrb + (size_t)2048 * 1920;         // 4*2048*64
  u16* vtb = kbuf + (size_t)4 * 2048 * 64;         // 4*64*2048
  float* gbuf = (float*)(vtb + (size_t)4 * 2048 * 64);  // 2048*16 f32
  float* rtab = gbuf + (size_t)2048 * 16;               // 2048*64 f32
  u16* aob = xb;  // xb dead after gemm1

  prep_all_k<<<4224, 256, 0, stream>>>(x, positions, Wq, Wk, Wv, Wvr, Wo, Wg,
                                       Wm, xb, WallT, WoT, rtab);
  gemm_bf16_k<128, true><<<dim3(15, 16), 512, 0, stream>>>(xb, WallT, qkvrb,
                                                           2048, 1920, 1024);
  postv_k<<<dim3(32, 4), 256, 0, stream>>>(bm, ksc, rtab, qkvrb, kbuf, vtb,
                                           gbuf);
  attn_k<<<dim3(16, 16), 512, 0, stream>>>(qkvrb, kbuf, vtb, gbuf, rtab, aob);
  gemm_bf16_k<64, false><<<dim3(8, 32), 512, 0, stream>>>(aob, WoT, out, 2048,
                                                          1024, 1024);
}

// Round 25
// 87.608 us; speedup vs baseline: 1.0254x; 1.0088x over previous
//
#include <hip/hip_runtime.h>
#include <hip/hip_bf16.h>
#include <math.h>

typedef unsigned short u16;
typedef unsigned int u32;
typedef __attribute__((ext_vector_type(8))) __bf16 bf16x8;
typedef __attribute__((ext_vector_type(4))) float f32x4;

__device__ inline u16 f2bf(float f) {
  u32 b = __float_as_uint(f);
  b += 0x7FFFu + ((b >> 16) & 1u);
  return (u16)(b >> 16);
}
__device__ inline float bf2f(u16 b) { return __uint_as_float((u32)b << 16); }

// async global->LDS, 16 bytes per lane; LDS dest = uniform base + lane*16
__device__ __forceinline__ void gll16(const void* gp, void* lp) {
  __builtin_amdgcn_global_load_lds(
      (const __attribute__((address_space(1))) void*)gp,
      (__attribute__((address_space(3))) void*)lp, 16, 0, 0);
}

// ---------------- fused prep: cvt | weight transposes | rope table ----------
// grid 4224 x 256: [0,1024) cvt x->xb ; [1024,3968) prep_w ; [3968,4224) rope
__global__ __launch_bounds__(256) void prep_all_k(
    const float* __restrict__ x, const int* __restrict__ positions,
    const float* __restrict__ Wq, const float* __restrict__ Wk,
    const float* __restrict__ Wv, const float* __restrict__ Wvr,
    const float* __restrict__ Wo, const float* __restrict__ Wg,
    const float* __restrict__ Wm, u16* __restrict__ xb,
    u16* __restrict__ WallT, u16* __restrict__ WoT, float* __restrict__ rtab) {
  __shared__ float tile[32][33];
  int bid = blockIdx.x, tid = threadIdx.x;
  if (bid < 1024) {  // ---- cvt ----
    int i = (bid * 256 + tid) * 8;
    float4 v0 = *(const float4*)&x[i];
    float4 v1 = *(const float4*)&x[i + 4];
    uint4 pk;
    pk.x = (u32)f2bf(v0.x) | ((u32)f2bf(v0.y) << 16);
    pk.y = (u32)f2bf(v0.z) | ((u32)f2bf(v0.w) << 16);
    pk.z = (u32)f2bf(v1.x) | ((u32)f2bf(v1.y) << 16);
    pk.w = (u32)f2bf(v1.z) | ((u32)f2bf(v1.w) << 16);
    *(uint4*)&xb[i] = pk;
    return;
  }
  if (bid >= 3968) {  // ---- rope table ----
    int idx = (bid - 3968) * 256 + tid;
    int s = idx >> 5, f = idx & 31;
    float inv = __expf(-(float)f * (9.210340371976184f / 32.f));
    float ang = (float)positions[s] * inv;
    rtab[(size_t)s * 64 + f] = cosf(ang);
    rtab[(size_t)s * 64 + 32 + f] = sinf(ang);
    return;
  }
  // ---- weight prep ----
  int b2 = bid - 1024;
  int k0 = (b2 & 31) * 32;
  int ybl = b2 >> 5;
  int tx = tid & 31, ty = tid >> 5;
  const float* src;
  int scol, sN, drow;
  u16* dst;
  if (ybl >= 60) {
    src = Wo; scol = (ybl - 60) * 32; sN = 1024; dst = WoT; drow = scol;
  } else {
    int n0 = ybl * 32;
    if (n0 >= 1792) {  // Wg/Wm/zero region, direct (no LDS)
#pragma unroll
      for (int j = 0; j < 4; ++j) {
        int n = n0 + ty * 4 + j, j2 = n - 1792, k = k0 + tx;
        float val = (j2 < 16) ? Wg[(size_t)k * 16 + j2]
                  : (j2 < 20) ? Wm[(size_t)k * 4 + (j2 - 16)] : 0.f;
        WallT[(size_t)n * 1024 + k] = f2bf(val);
      }
      return;
    }
    dst = WallT; drow = n0;
    if (n0 < 1024) { src = Wq; scol = n0; sN = 1024; }
    else if (n0 < 1280) { src = Wk; scol = n0 - 1024; sN = 256; }
    else if (n0 < 1536) { src = Wv; scol = n0 - 1280; sN = 256; }
    else { src = Wvr; scol = n0 - 1536; sN = 256; }
  }
#pragma unroll
  for (int j = 0; j < 4; ++j)
    tile[ty * 4 + j][tx] = src[(size_t)(k0 + ty * 4 + j) * sN + scol + tx];
  __syncthreads();
#pragma unroll
  for (int j = 0; j < 4; ++j)
    dst[(size_t)(drow + ty * 4 + j) * 1024 + k0 + tx] = f2bf(tile[tx][ty * 4 + j]);
}

// ---------------- bf16 MFMA GEMM, LDS double-buffered (T3 min-2-phase) ------
template <int BM, bool BF16_OUT>
__global__ __launch_bounds__(512) void gemm_bf16_k(
    const u16* __restrict__ A, const u16* __restrict__ Bt, void* __restrict__ Cv,
    int M, int N, int K) {
  constexpr int MI = BM / 32;
  __shared__ __align__(16) u16 As[2][BM * 64];
  __shared__ __align__(16) u16 Bs[2][128 * 64];
  int tid = threadIdx.x;
  int w = tid >> 6, l = tid & 63;
  int wr = w >> 2, wc = w & 3;
  int lr = l & 15, lg = l >> 4;
  int lrow = l >> 3, lcol = (l & 7) * 8;  // staging decomposition
  int m0 = blockIdx.y * BM, n0 = blockIdx.x * 128;
  f32x4 zero = {0.f, 0.f, 0.f, 0.f};
  f32x4 acc[MI][2];
#pragma unroll
  for (int mi = 0; mi < MI; ++mi)
#pragma unroll
    for (int ni = 0; ni < 2; ++ni) acc[mi][ni] = zero;

  auto gstage = [&](int buf, int kt) {
#pragma unroll
    for (int ts = 0; ts < BM / 64; ++ts) {
      int seg = ts * 8 + w;
      gll16(&A[(size_t)(m0 + seg * 8 + lrow) * K + kt + lcol],
            &As[buf][seg * 512]);
    }
#pragma unroll
    for (int ts = 0; ts < 2; ++ts) {
      int seg = ts * 8 + w;
      gll16(&Bt[(size_t)(n0 + seg * 8 + lrow) * K + kt + lcol],
            &Bs[buf][seg * 512]);
    }
  };

  gstage(0, 0);
  __syncthreads();
  int nt = K >> 6;
#pragma unroll 1
  for (int t = 0; t < nt; ++t) {
    int cur = t & 1;
    if (t + 1 < nt) gstage(cur ^ 1, (t + 1) * 64);
#pragma unroll
    for (int kw = 0; kw < 2; ++kw) {
      bf16x8 af[MI], bfr[2];
#pragma unroll
      for (int mi = 0; mi < MI; ++mi)
        af[mi] = *(const bf16x8*)&As[cur][(wr * (BM / 2) + mi * 16 + lr) * 64 + kw * 32 + lg * 8];
#pragma unroll
      for (int ni = 0; ni < 2; ++ni)
        bfr[ni] = *(const bf16x8*)&Bs[cur][(wc * 32 + ni * 16 + lr) * 64 + kw * 32 + lg * 8];
#pragma unroll
      for (int mi = 0; mi < MI; ++mi)
#pragma unroll
        for (int ni = 0; ni < 2; ++ni)
          acc[mi][ni] = __builtin_amdgcn_mfma_f32_16x16x32_bf16(
              af[mi], bfr[ni], acc[mi][ni], 0, 0, 0);
    }
    __syncthreads();  // single barrier: readers done + next-buf loads drained
  }
#pragma unroll
  for (int mi = 0; mi < MI; ++mi)
#pragma unroll
    for (int ni = 0; ni < 2; ++ni)
#pragma unroll
      for (int r = 0; r < 4; ++r) {
        int row = m0 + wr * (BM / 2) + mi * 16 + lg * 4 + r;
        int col = n0 + wc * 32 + ni * 16 + lr;
        if (BF16_OUT)
          ((u16*)Cv)[(size_t)row * N + col] = f2bf(acc[mi][ni][r]);
        else
          ((float*)Cv)[(size_t)row * N + col] = acc[mi][ni][r];
      }
}

// ---------------- fused postprocess + v transpose ---------------------------
#define TPAD 66
__global__ __launch_bounds__(256) void postv_k(
    const float* __restrict__ bm, const float* __restrict__ ksc,
    const float* __restrict__ rtab, const u16* __restrict__ qkvrb,
    u16* __restrict__ kb, u16* __restrict__ vtb, float* __restrict__ g_out) {
  __shared__ u16 tile[64 * TPAD];
  int s0 = blockIdx.x * 64, h = blockIdx.y;
  int t = threadIdx.x;
  int sl = t >> 2, db = (t & 3) * 16;
  int s = s0 + sl;
  const u16* row = qkvrb + (size_t)s * 1920;
  if (h == 0) {  // g sigmoids for this s-tile (16 heads x 64 rows)
#pragma unroll
    for (int j = 0; j < 4; ++j) {
      int idx = j * 256 + t;
      int sg = s0 + (idx >> 4), hh = idx & 15;
      g_out[sg * 16 + hh] =
          1.f / (1.f + __expf(-bf2f(qkvrb[(size_t)sg * 1920 + 1792 + hh])));
    }
  }
  // ---- k: RMSNorm * k_scale + RoPE -> kb [h][s][d] ----
  float kvv[16];
  float ssq = 0.f;
  {
    uint4 kr0 = *(const uint4*)&row[1024 + h * 64 + db];
    uint4 kr1 = *(const uint4*)&row[1024 + h * 64 + db + 8];
    const u16* p0 = (const u16*)&kr0;
    const u16* p1 = (const u16*)&kr1;
#pragma unroll
    for (int j = 0; j < 8; ++j) {
      kvv[j] = bf2f(p0[j]);
      ssq += kvv[j] * kvv[j];
    }
#pragma unroll
    for (int j = 0; j < 8; ++j) {
      kvv[8 + j] = bf2f(p1[j]);
      ssq += kvv[8 + j] * kvv[8 + j];
    }
  }
  ssq += __shfl_xor(ssq, 1);
  ssq += __shfl_xor(ssq, 2);
  float rinv = 1.f / sqrtf(ssq * (1.f / 64.f) + 1e-8f);
  const float* tr = rtab + (size_t)s * 64;
  float cs[8], sn[8];
  *(float4*)cs = *(const float4*)&tr[db >> 1];
  *(float4*)(cs + 4) = *(const float4*)&tr[(db >> 1) + 4];
  *(float4*)sn = *(const float4*)&tr[32 + (db >> 1)];
  *(float4*)(sn + 4) = *(const float4*)&tr[32 + (db >> 1) + 4];
  float scl[16];
  *(float4*)scl = *(const float4*)&ksc[h * 64 + db];
  *(float4*)(scl + 4) = *(const float4*)&ksc[h * 64 + db + 4];
  *(float4*)(scl + 8) = *(const float4*)&ksc[h * 64 + db + 8];
  *(float4*)(scl + 12) = *(const float4*)&ksc[h * 64 + db + 12];
  {
    u16 outk[16];
#pragma unroll
    for (int j = 0; j < 8; ++j) {
      float e = kvv[2 * j] * rinv * scl[2 * j];
      float o = kvv[2 * j + 1] * rinv * scl[2 * j + 1];
      outk[2 * j] = f2bf(e * cs[j] - o * sn[j]);
      outk[2 * j + 1] = f2bf(o * cs[j] + e * sn[j]);
    }
    u16* kdst = kb + ((size_t)h * 2048 + s) * 64 + db;
    *(uint4*)kdst = *(uint4*)outk;
    *(uint4*)(kdst + 8) = *(uint4*)(outk + 8);
  }
  // ---- v: mix -> LDS tile ----
  {
    float mixv = 1.f / (1.f + __expf(-(bf2f(row[1808 + h]) + bm[h])));
    uint4 vr0 = *(const uint4*)&row[1280 + h * 64 + db];
    uint4 vr1 = *(const uint4*)&row[1280 + h * 64 + db + 8];
    uint4 rr0 = *(const uint4*)&row[1536 + h * 64 + db];
    uint4 rr1 = *(const uint4*)&row[1536 + h * 64 + db + 8];
    const u16* vp0 = (const u16*)&vr0;
    const u16* vp1 = (const u16*)&vr1;
    const u16* rp0 = (const u16*)&rr0;
    const u16* rp1 = (const u16*)&rr1;
#pragma unroll
    for (int j = 0; j < 8; ++j) {
      float vv = bf2f(vp0[j]);
      tile[sl * TPAD + db + j] = f2bf(vv + mixv * (bf2f(rp0[j]) - vv));
    }
#pragma unroll
    for (int j = 0; j < 8; ++j) {
      float vv = bf2f(vp1[j]);
      tile[sl * TPAD + db + 8 + j] = f2bf(vv + mixv * (bf2f(rp1[j]) - vv));
    }
  }
  __syncthreads();
  // ---- transpose-write vtb [h][d][s] ----
  {
    int d = t >> 2, sb = (t & 3) * 16;
    u16 vals[16];
#pragma unroll
    for (int j = 0; j < 16; ++j) vals[j] = tile[(sb + j) * TPAD + d];
    uint4 a, b;
    a.x = (u32)vals[0] | ((u32)vals[1] << 16);
    a.y = (u32)vals[2] | ((u32)vals[3] << 16);
    a.z = (u32)vals[4] | ((u32)vals[5] << 16);
    a.w = (u32)vals[6] | ((u32)vals[7] << 16);
    b.x = (u32)vals[8] | ((u32)vals[9] << 16);
    b.y = (u32)vals[10] | ((u32)vals[11] << 16);
    b.z = (u32)vals[12] | ((u32)vals[13] << 16);
    b.w = (u32)vals[14] | ((u32)vals[15] << 16);
    u16* dst = vtb + ((size_t)h * 64 + d) * 2048 + s0 + sb;
    *(uint4*)dst = a;
    *(uint4*)(dst + 8) = b;
  }
}

// ---------------- MFMA causal attention: CHUNK-PAIR iterations --------------
// Group g owns chunk-pairs {4i+2g, 4i+2g+1}. Per iter: stage next pair
// (issued BEFORE compute -> latency hides under ~1200cyc compute, r20
// pattern), compute two INDEPENDENT chunks (chain-level ILP: chunk1's QK
// overlaps chunk0's softmax; PV0 overlaps softmax1), ONE barrier. Barriers
// 17 -> 9 per half. Stage indices clamp to rb (uniform counts, masked).
// LDS 144KB: 2grp x 2pair-slots x 32KB + 16KB Pw. q RoPE in-register.
__global__ __launch_bounds__(512) void attn_k(
    const u16* __restrict__ qkvrb, const u16* __restrict__ kb,
    const u16* __restrict__ vtb, const float* __restrict__ g,
    const float* __restrict__ rtab, u16* __restrict__ aob) {
  __shared__ __align__(16) u16 smem[73728];  // 144 KB
  int head = blockIdx.x, hkv = head >> 2;
  int tid = threadIdx.x;
  int w = tid >> 6, l = tid & 63;
  int grp = w >> 2, wi = w & 3;
  int lr = l & 15, lg = l >> 4;
  int gtid = wi * 64 + l;
  u16* GrpBase = smem + grp * 32768;                 // 2 slots x 16384 u16
  u32* pw = (u32*)(smem + 65536) + (size_t)w * 512;  // per-wave 16 x 32 u32
  float* mbuf = (float*)smem;  // merge: 256 x 17 f32 (17.4 KB, aliases)
  f32x4 zero = {0.f, 0.f, 0.f, 0.f};
  const float L2E = 1.4426950408889634f;   // log2(e)
  const float NB = -72.13475204444817f;    // -50 * log2(e)
  int sw = (lr & 7) << 2;                  // P-tile column swizzle
  int u0 = ((lg ^ (lr & 7)) << 3);         // K/V physical u16 offset of unit
  int srow = l >> 3;
  int sunit = (l & 7) ^ srow;
  const u16* ksrc = kb + ((size_t)hkv * 2048 + srow) * 64 + sunit * 8;
  const u16* vsrc = vtb + ((size_t)(hkv * 64 + srow)) * 2048 + sunit * 8;
#pragma unroll 1
  for (int half = 0; half < 2; ++half) {
    int rb = half ? (int)blockIdx.y : (31 - (int)blockIdx.y);
    int row0 = rb * 64;
    int qglob = row0 + wi * 16 + lr;
    // ---- q fragment build with in-register RoPE + 0.125 scale ----
    const u16* qrow = qkvrb + (size_t)qglob * 1920 + head * 64;
    const float* trq = rtab + (size_t)qglob * 64;
    bf16x8 qf0, qf1;
    {
      float ce0[4], se0[4], ce1[4], se1[4];
      *(float4*)ce0 = *(const float4*)&trq[lg * 4];
      *(float4*)se0 = *(const float4*)&trq[32 + lg * 4];
      *(float4*)ce1 = *(const float4*)&trq[16 + lg * 4];
      *(float4*)se1 = *(const float4*)&trq[48 + lg * 4];
      uint4 qr0 = *(const uint4*)&qrow[lg * 8];
      uint4 qr1 = *(const uint4*)&qrow[32 + lg * 8];
      const u16* qp0 = (const u16*)&qr0;
      const u16* qp1 = (const u16*)&qr1;
      union { u32 w[4]; bf16x8 v; } b0, b1;
#pragma unroll
      for (int j = 0; j < 4; ++j) {
        float e0 = bf2f(qp0[2 * j]), e1 = bf2f(qp0[2 * j + 1]);
        float r0 = (e0 * ce0[j] - e1 * se0[j]) * 0.125f;
        float r1 = (e1 * ce0[j] + e0 * se0[j]) * 0.125f;
        b0.w[j] = (u32)f2bf(r0) | ((u32)f2bf(r1) << 16);
        float f0 = bf2f(qp1[2 * j]), f1 = bf2f(qp1[2 * j + 1]);
        float t0 = (f0 * ce1[j] - f1 * se1[j]) * 0.125f;
        float t1 = (f1 * ce1[j] + f0 * se1[j]) * 0.125f;
        b1.w[j] = (u32)f2bf(t0) | ((u32)f2bf(t1) << 16);
      }
      qf0 = b0.v;
      qf1 = b1.v;
    }
    f32x4 acc_o[4];
#pragma unroll
    for (int nd = 0; nd < 4; ++nd) acc_o[nd] = zero;
    float l_part = 0.f;
    // stage a pair of chunks (c0, c0+1) into slot; indices clamped to rb
    auto stagePair = [&](int slot, int c0) {
      u16* S = GrpBase + slot * 16384;
      int cA = c0 <= rb ? c0 : rb;
      int cB = c0 + 1 <= rb ? c0 + 1 : rb;
#pragma unroll
      for (int t = 0; t < 2; ++t) {
        int seg = wi * 2 + t;
        gll16(ksrc + (size_t)(cA * 64 + seg * 8) * 64, S + seg * 512);
        gll16(vsrc + (size_t)(seg * 8) * 2048 + cA * 64, S + 4096 + seg * 512);
        gll16(ksrc + (size_t)(cB * 64 + seg * 8) * 64, S + 8192 + seg * 512);
        gll16(vsrc + (size_t)(seg * 8) * 2048 + cB * 64,
              S + 12288 + seg * 512);
      }
    };
    int c = grp * 2;
    stagePair(0, c);
    __syncthreads();
    int nmax = (rb >> 2) + 1;
#pragma unroll 1
    for (int i = 0; i < nmax; ++i, c += 4) {
      stagePair((i + 1) & 1, c + 4);  // issue-early; drained at the barrier
      u16* slotBase = GrpBase + (i & 1) * 16384;
      __builtin_amdgcn_s_setprio(1);
#pragma unroll
      for (int h = 0; h < 2; ++h) {
        int ch = c + h;
        if (ch <= rb) {
          u16* Ks = slotBase + h * 8192;
          u16* Vt = Ks + 4096;
          int kbase = ch * 64;
          // swapped QK^T: A=K (row=key, k=d), B=q (col=q) -> D[key][q]
          f32x4 sa[4];
#pragma unroll
          for (int ni = 0; ni < 4; ++ni) {
            const u16* kp = &Ks[(ni * 16 + lr) * 64];
            bf16x8 a0 = *(const bf16x8*)&kp[u0];
            bf16x8 a1 = *(const bf16x8*)&kp[u0 ^ 32];
            f32x4 t = __builtin_amdgcn_mfma_f32_16x16x32_bf16(a0, qf0, zero, 0, 0, 0);
            sa[ni] = __builtin_amdgcn_mfma_f32_16x16x32_bf16(a1, qf1, t, 0, 0, 0);
          }
          bool diag = (ch == rb);
          // p = exp(50*tanh(s/50)-50) via Taylor poly (1 exp2)
#pragma unroll
          for (int ni = 0; ni < 4; ++ni) {
            float pv[4];
#pragma unroll
            for (int r = 0; r < 4; ++r) {
              float sv = fminf(fmaxf(sa[ni][r], -60.f), 60.f);
              float t2 = sv * 0.02f;
              float u = t2 * t2;
              float cl = sv * fmaf(u, fmaf(u, 0.13333333f, -0.33333333f), 1.f);
              float p = __builtin_amdgcn_exp2f(fmaf(cl, L2E, NB));
              if (diag && (kbase + ni * 16 + lg * 4 + r) > qglob) p = 0.f;
              pv[r] = p;
              l_part += p;
            }
            u32 w0, w1;
            asm("v_cvt_pk_bf16_f32 %0, %1, %2" : "=v"(w0) : "v"(pv[0]), "v"(pv[1]));
            asm("v_cvt_pk_bf16_f32 %0, %1, %2" : "=v"(w1) : "v"(pv[2]), "v"(pv[3]));
            uint2 pr;
            pr.x = w0;
            pr.y = w1;
            *(uint2*)&pw[lr * 32 + ((ni * 8 + lg * 2) ^ sw)] = pr;
          }
          // read PV A-fragments back (wave-internal LDS: in-order)
          bf16x8 pfa = *(const bf16x8*)&pw[lr * 32 + ((lg * 4) ^ sw)];
          bf16x8 pfb = *(const bf16x8*)&pw[lr * 32 + ((16 + lg * 4) ^ sw)];
          // PV: A=P (row=q, k=key), B=V^T (col=d, k=key)
#pragma unroll
          for (int nd = 0; nd < 4; ++nd) {
            const u16* vp = &Vt[(nd * 16 + lr) * 64];
            bf16x8 v0 = *(const bf16x8*)&vp[u0];
            bf16x8 v1 = *(const bf16x8*)&vp[u0 ^ 32];
            acc_o[nd] = __builtin_amdgcn_mfma_f32_16x16x32_bf16(pfa, v0, acc_o[nd], 0, 0, 0);
            acc_o[nd] = __builtin_amdgcn_mfma_f32_16x16x32_bf16(pfb, v1, acc_o[nd], 0, 0, 0);
          }
        }
      }
      __builtin_amdgcn_s_setprio(0);
      __syncthreads();  // one barrier per PAIR (drains next pair's loads)
    }
    // reduce l within wave (sum 4 lg copies of each q-row)
    l_part += __shfl_xor(l_part, 16);
    l_part += __shfl_xor(l_part, 32);
    // merge groups via LDS (buffers dead after final loop barrier)
    if (grp == 1) {
      float* mb = mbuf + (size_t)gtid * 17;
#pragma unroll
      for (int nd = 0; nd < 4; ++nd)
#pragma unroll
        for (int r = 0; r < 4; ++r) mb[nd * 4 + r] = acc_o[nd][r];
      mb[16] = l_part;
    }
    __syncthreads();
    if (grp == 0) {
      const float* mb = mbuf + (size_t)gtid * 17;
      float lt = l_part + mb[16];
#pragma unroll
      for (int r = 0; r < 4; ++r) {
        int row = row0 + wi * 16 + lg * 4 + r;
        float lv = __shfl(lt, lg * 4 + r);
        float sc = g[row * 16 + head] * __builtin_amdgcn_rcpf(lv);
#pragma unroll
        for (int nd = 0; nd < 4; ++nd)
          aob[(size_t)row * 1024 + head * 64 + nd * 16 + lr] =
              f2bf((acc_o[nd][r] + mb[nd * 4 + r]) * sc);
      }
    }
    __syncthreads();  // mbuf reads done before next half restages buffers
  }
}

extern "C" void kernel_launch(void* const* d_in, const int* in_sizes, int n_in,
                              void* d_out, int out_size, void* d_ws,
                              size_t ws_size, hipStream_t stream) {
  const float* x = (const float*)d_in[0];
  const int* positions = (const int*)d_in[1];
  const float* Wq = (const float*)d_in[3];
  const float* Wk = (const float*)d_in[4];
  const float* Wv = (const float*)d_in[5];
  const float* Wo = (const float*)d_in[6];
  const float* Wg = (const float*)d_in[7];
  const float* Wm = (const float*)d_in[8];
  const float* bm = (const float*)d_in[9];
  const float* Wvr = (const float*)d_in[10];
  const float* ksc = (const float*)d_in[11];
  float* out = (float*)d_out;

  u16* xb = (u16*)d_ws;                            // 2048*1024
  u16* WallT = xb + (size_t)2048 * 1024;           // 1920*1024
  u16* WoT = WallT + (size_t)1920 * 1024;          // 1024*1024
  u16* qkvrb = WoT + (size_t)1024 * 1024;          // 2048*1920
  u16* kbuf = qkvrb + (size_t)2048 * 1920;         // 4*2048*64
  u16* vtb = kbuf + (size_t)4 * 2048 * 64;         // 4*64*2048
  float* gbuf = (float*)(vtb + (size_t)4 * 2048 * 64);  // 2048*16 f32
  float* rtab = gbuf + (size_t)2048 * 16;               // 2048*64 f32
  u16* aob = xb;  // xb dead after gemm1

  prep_all_k<<<4224, 256, 0, stream>>>(x, positions, Wq, Wk, Wv, Wvr, Wo, Wg,
                                       Wm, xb, WallT, WoT, rtab);
  gemm_bf16_k<128, true><<<dim3(15, 16), 512, 0, stream>>>(xb, WallT, qkvrb,
                                                           2048, 1920, 1024);
  postv_k<<<dim3(32, 4), 256, 0, stream>>>(bm, ksc, rtab, qkvrb, kbuf, vtb,
                                           gbuf);
  attn_k<<<dim3(16, 16), 512, 0, stream>>>(qkvrb, kbuf, vtb, gbuf, rtab, aob);
  gemm_bf16_k<64, false><<<dim3(8, 32), 512, 0, stream>>>(aob, WoT, out, 2048,
                                                          1024, 1024);
}